// Round 2
// baseline (164.604 us; speedup 1.0000x reference)
//
#include <hip/hip_runtime.h>
#include <math.h>
#include <stdint.h>

#define B_ 4
#define N_ 250000
#define P_ 1000
#define G_ 32
#define C_ 81
#define RPN_BATCH 256
#define ROI_BATCH 128

#define ABLK 1024                                   // anchors per block
#define NBA ((N_ + ABLK - 1) / ABLK)                // 245
#define DETB 4                                      // det blocks per batch (32 ROIs each)

__device__ __forceinline__ float iou_one(float a0, float a1, float a2, float a3,
                                         float areaA,
                                         float b0, float b1, float b2, float b3) {
    float ltx = fmaxf(a0, b0), lty = fmaxf(a1, b1);
    float rbx = fminf(a2, b2), rby = fminf(a3, b3);
    float w = fmaxf(rbx - ltx, 0.f), h = fmaxf(rby - lty, 0.f);
    float inter = w * h;
    float areaB = (b2 - b0) * (b3 - b1);
    return inter / (areaA + areaB - inter + 1e-6f);
}

__device__ __forceinline__ float smooth_l1(float x) {
    float ax = fabsf(x);
    return (ax < 1.f) ? 0.5f * x * x : ax - 0.5f;
}

// Kernel 1: fused RPN assign (blocks x < NBA) + detection loss (blocks x >= NBA).
// Per-gt winners go straight to gtWin[B][G] via u64 atomicMax (iou bits | ~idx),
// replacing the blockBest array + middle reduction kernel.
__global__ void __launch_bounds__(256, 4) rpn_assign_det(
        const float* __restrict__ anchors, const float* __restrict__ gt_boxes,
        const int* __restrict__ gt_labels, const float* __restrict__ proposals,
        const float* __restrict__ cls_scores, const float* __restrict__ bbox_deltas,
        int8_t* __restrict__ labels, int* __restrict__ posCnt, int* __restrict__ negCnt,
        unsigned long long* __restrict__ gtWin, float* __restrict__ detPart,
        float* __restrict__ out, int out_size) {
    int b = blockIdx.y, tid = threadIdx.x;
    int lane = tid & 63, wave = tid >> 6;

    if (blockIdx.x >= NBA) {
        // ---------------- detection-loss path (256 threads, 32 ROIs) ----------------
        int h = blockIdx.x - NBA;                 // which quarter of the 128 ROIs
        __shared__ float sgt[G_ * 4];
        __shared__ int sgl[G_];
        __shared__ short sassign[P_];
        __shared__ unsigned char sargm[P_];
        __shared__ int ssamp[ROI_BATCH];
        __shared__ int swd[4];
        __shared__ float sc[4], srg[4];
        if (tid < G_ * 4) sgt[tid] = gt_boxes[b * G_ * 4 + tid];
        if (tid < G_) sgl[tid] = gt_labels[b * G_ + tid];
        __syncthreads();

        // phase 1: assign proposals (4 per thread, blocked so scan order = index order)
        int myPos = 0;
        int labj[4];
#pragma unroll
        for (int j = 0; j < 4; ++j) {
            int p = tid * 4 + j;
            int labp = 0, am = 0;
            if (p < P_) {
                float4 A = ((const float4*)proposals)[b * P_ + p];
                float areaA = (A.z - A.x) * (A.w - A.y);
                float best = -1.f;
#pragma unroll 8
                for (int g = 0; g < G_; ++g) {
                    float iou = iou_one(A.x, A.y, A.z, A.w, areaA,
                                        sgt[g * 4], sgt[g * 4 + 1], sgt[g * 4 + 2], sgt[g * 4 + 3]);
                    if (iou > best) { best = iou; am = g; }
                }
                labp = (best >= 0.5f) ? sgl[am] : 0;
                sassign[p] = (short)labp;
                sargm[p] = (unsigned char)am;
                labj[j] = labp;
                myPos += (labp > 0);
            } else {
                labj[j] = -1;
            }
        }

        // phase 2: sampling ranks (wave scan + block scan over 4 waves)
        int inc = myPos;
        for (int off = 1; off < 64; off <<= 1) {
            int v = __shfl_up(inc, off);
            if (lane >= off) inc += v;
        }
        if (lane == 63) swd[wave] = inc;
        __syncthreads();
        int basew = 0, total = 0;
        for (int w = 0; w < 4; ++w) { if (w < wave) basew += swd[w]; total += swd[w]; }
        int pp = basew + inc - myPos;             // exclusive pos-prefix at proposal 4*tid
        int npos_kept = min(total, ROI_BATCH / 4);
        int nneg_total = P_ - total;
#pragma unroll
        for (int j = 0; j < 4; ++j) {
            int p = tid * 4 + j;
            if (labj[j] < 0) break;
            int slot;
            if (labj[j] > 0) {
                slot = (pp < ROI_BATCH / 4) ? pp : npos_kept + nneg_total + (pp - ROI_BATCH / 4);
                pp++;
            } else {
                slot = npos_kept + (p - pp);
            }
            if (slot < ROI_BATCH) ssamp[slot] = p;
        }
        int np_det = npos_kept + max(0, ROI_BATCH - npos_kept - nneg_total);
        __syncthreads();

        // phase 3: softmax CE straight from global (cls rows are L2-resident),
        // 2 rows per iteration for load-latency overlap; row[t] via shuffle.
        int rowBase = h * (ROI_BATCH / DETB) + wave * 8;
        float clsAcc = 0.f;
        for (int k = 0; k < 8; k += 2) {
            int s0 = ssamp[rowBase + k], s1 = ssamp[rowBase + k + 1];
            const float* r0 = cls_scores + ((size_t)(b * P_ + s0)) * C_;
            const float* r1 = cls_scores + ((size_t)(b * P_ + s1)) * C_;
            float a1 = r0[lane], b1 = r1[lane];
            float a2 = (lane < C_ - 64) ? r0[64 + lane] : -INFINITY;
            float b2 = (lane < C_ - 64) ? r1[64 + lane] : -INFINITY;
            float m0 = fmaxf(a1, a2), m1 = fmaxf(b1, b2);
            for (int mm = 32; mm >= 1; mm >>= 1) {
                m0 = fmaxf(m0, __shfl_xor(m0, mm));
                m1 = fmaxf(m1, __shfl_xor(m1, mm));
            }
            float e0 = expf(a1 - m0) + ((lane < C_ - 64) ? expf(a2 - m0) : 0.f);
            float e1 = expf(b1 - m1) + ((lane < C_ - 64) ? expf(b2 - m1) : 0.f);
            for (int mm = 32; mm >= 1; mm >>= 1) {
                e0 += __shfl_xor(e0, mm);
                e1 += __shfl_xor(e1, mm);
            }
            int t0 = sassign[s0], t1 = sassign[s1];
            int q0 = (t0 < 64) ? t0 : t0 - 64;
            int q1 = (t1 < 64) ? t1 : t1 - 64;
            float lo0 = __shfl(a1, q0), hi0 = __shfl(a2, q0);
            float lo1 = __shfl(b1, q1), hi1 = __shfl(b2, q1);
            float v0 = (t0 < 64) ? lo0 : hi0;
            float v1 = (t1 < 64) ? lo1 : hi1;
            if (lane == 0)
                clsAcc += -(v0 - m0 - logf(e0)) - (v1 - m1 - logf(e1));
        }

        // reg loss: one lane per ROI of this wave's 8 rows (parallel float4 loads)
        float regAcc = 0.f;
        if (lane < 8) {
            int r = rowBase + lane;
            int s = ssamp[r];
            int t = sassign[s];
            if (t > 0) {
                int g = sargm[s];
                float4 A = ((const float4*)proposals)[b * P_ + s];
                float t0g = sgt[g * 4], t1g = sgt[g * 4 + 1];
                float t2g = sgt[g * 4 + 2], t3g = sgt[g * 4 + 3];
                float wa = A.z - A.x, ha = A.w - A.y;
                float xa = A.x + 0.5f * wa, ya = A.y + 0.5f * ha;
                float wt = t2g - t0g, ht = t3g - t1g;
                float xt = t0g + 0.5f * wt, yt = t1g + 0.5f * ht;
                const float4 pd = *(const float4*)(bbox_deltas +
                        ((size_t)(b * P_ + s)) * (4 * C_) + 4 * t);
                regAcc = smooth_l1(pd.x - (xt - xa) / wa) + smooth_l1(pd.y - (yt - ya) / ha) +
                         smooth_l1(pd.z - logf(wt / wa + 1e-6f)) +
                         smooth_l1(pd.w - logf(ht / ha + 1e-6f));
            }
        }
        for (int mm = 32; mm >= 1; mm >>= 1) regAcc += __shfl_xor(regAcc, mm);
        if (lane == 0) { sc[wave] = clsAcc; srg[wave] = regAcc; }
        __syncthreads();
        if (tid == 0) {
            float cp = sc[0] + sc[1] + sc[2] + sc[3];
            float rp = srg[0] + srg[1] + srg[2] + srg[3];
            detPart[b * DETB + h] = cp / (float)ROI_BATCH +
                ((np_det > 0) ? rp / fmaxf((float)np_det * 4.f, 1.f) : 0.f);
        }
        return;
    }

    // ---------------- RPN assign path ----------------
    __shared__ float4 sA[ABLK];                 // 16 KB
    __shared__ unsigned char sPart[4][ABLK];    // 4 KB
    __shared__ int sCnt[8];

    int base = blockIdx.x * ABLK;

    if (blockIdx.x == 0 && b == 0) {
        for (int i = tid; i < out_size; i += 256) out[i] = 0.f;
    }

    for (int t = tid; t < ABLK; t += 256) {
        int ai = base + t;
        float4 v = make_float4(0.f, 0.f, 0.f, 0.f);
        if (ai < N_) v = ((const float4*)anchors)[ai];
        sA[t] = v;
    }
    __syncthreads();

    int waveu = __builtin_amdgcn_readfirstlane(wave);   // provably wave-uniform

    const float4* gt4 = (const float4*)gt_boxes + b * G_ + waveu * 8;
    float g0[8], g1[8], g2[8], g3[8], gae[8];
#pragma unroll
    for (int j = 0; j < 8; ++j) {
        float4 g = gt4[j];
        g0[j] = g.x; g1[j] = g.y; g2[j] = g.z; g3[j] = g.w;
        gae[j] = (g.z - g.x) * (g.w - g.y) + 1e-6f;
    }

    float bi[8], bd[8]; int bx[8];
#pragma unroll
    for (int j = 0; j < 8; ++j) { bi[j] = 0.f; bd[j] = 1.f; bx[j] = 0; }

    for (int k = 0; k < ABLK / 64; ++k) {
        int a = k * 64 + lane;
        float4 A = sA[a];
        float areaA = (A.z - A.x) * (A.w - A.y);
        int gidx = base + a;
        float acc03 = 1e30f, acc07 = 1e30f;
#pragma unroll
        for (int j = 0; j < 8; ++j) {
            float ltx = fmaxf(A.x, g0[j]), lty = fmaxf(A.y, g1[j]);
            float rbx = fminf(A.z, g2[j]), rby = fminf(A.w, g3[j]);
            float w = fmaxf(rbx - ltx, 0.f), h = fmaxf(rby - lty, 0.f);
            float inter = w * h;
            float d = (areaA + gae[j]) - inter;
            acc03 = fminf(acc03, fmaf(0.3f, d, -inter)); // >0 => iou<0.3
            acc07 = fminf(acc07, fmaf(0.7f, d, -inter)); // <0 => iou>0.7
            float p1 = inter * bd[j], p2 = bi[j] * d;
            if (p1 > p2) { bi[j] = inter; bd[j] = d; bx[j] = gidx; }
        }
        sPart[wave][a] = (unsigned char)(((acc07 < 0.f) ? 2 : 0) | ((acc03 > 0.f) ? 1 : 0));
    }

#pragma unroll
    for (int j = 0; j < 8; ++j) {
        float i_ = bi[j], d_ = bd[j]; int x_ = bx[j];
        for (int m = 32; m >= 1; m >>= 1) {
            float oi = __shfl_xor(i_, m), od = __shfl_xor(d_, m);
            int ox = __shfl_xor(x_, m);
            float pa = oi * d_, pb = i_ * od;
            bool take = (pa > pb) || (pa == pb && ox < x_);
            if (take) { i_ = oi; d_ = od; x_ = ox; }
        }
        if (lane == 0) {
            float iou = i_ / d_;
            unsigned long long pk =
                (((unsigned long long)__float_as_uint(iou)) << 32) |
                (unsigned)(0xFFFFFFFFu - (unsigned)x_);
            atomicMax(&gtWin[(size_t)b * G_ + wave * 8 + j], pk);
        }
    }
    __syncthreads();

    unsigned u0 = ((const unsigned*)&sPart[0][0])[tid];
    unsigned u1 = ((const unsigned*)&sPart[1][0])[tid];
    unsigned u2 = ((const unsigned*)&sPart[2][0])[tid];
    unsigned u3 = ((const unsigned*)&sPart[3][0])[tid];
    unsigned andb = u0 & u1 & u2 & u3;
    unsigned orb  = u0 | u1 | u2 | u3;
    int gbase = base + tid * 4;
    unsigned outw = 0; int cp = 0, cn = 0;
#pragma unroll
    for (int j = 0; j < 4; ++j) {
        int above = (orb >> (8 * j + 1)) & 1;
        int below = (andb >> (8 * j)) & 1;
        int lab = above ? 1 : (below ? 0 : -1);
        if (gbase + j < N_) { cp += (lab == 1); cn += (lab == 0); }
        outw |= ((unsigned)(unsigned char)(char)lab) << (8 * j);
    }
    if (gbase < N_)
        ((unsigned*)labels)[(((size_t)b * N_ + base) >> 2) + tid] = outw;

    for (int m = 32; m >= 1; m >>= 1) { cp += __shfl_xor(cp, m); cn += __shfl_xor(cn, m); }
    if (lane == 0) { sCnt[wave] = cp; sCnt[4 + wave] = cn; }
    __syncthreads();
    if (tid == 0) {
        posCnt[b * NBA + blockIdx.x] = sCnt[0] + sCnt[1] + sCnt[2] + sCnt[3];
        negCnt[b * NBA + blockIdx.x] = sCnt[4] + sCnt[5] + sCnt[6] + sCnt[7];
    }
}

// Kernel 2 (was kernel 3): each block re-derives promote + scan locally
// (2 KB of counts + 32 winners), early-exits if it holds no sampled anchors,
// else computes BCE/reg partials, pre-divided, atomically into out.
__global__ void __launch_bounds__(256) rpn_sample(
        const int8_t* __restrict__ labels, const float* __restrict__ rpn_scores,
        const float* __restrict__ rpn_deltas, const float* __restrict__ anchors,
        const float* __restrict__ gt_boxes,
        const int* __restrict__ posCnt, const int* __restrict__ negCnt,
        const unsigned long long* __restrict__ gtWin,
        const float* __restrict__ detPart, float* __restrict__ out) {
    int b = blockIdx.y, tid = threadIdx.x;
    int base = blockIdx.x * ABLK;
    __shared__ float sg[G_ * 4];
    __shared__ int sp[256], sn[256];
    __shared__ unsigned swin[G_];
    __shared__ int sBase[6];     // posBase, negBase, totP, totN, cntP_blk, cntN_blk
    __shared__ int swP[4], swN[4];
    __shared__ float sred[8];

    if (tid < G_ * 4) sg[tid] = gt_boxes[b * G_ * 4 + tid];
    if (tid < G_) {
        unsigned long long v = gtWin[(size_t)b * G_ + tid];
        swin[tid] = 0xFFFFFFFFu - (unsigned)(v & 0xFFFFFFFFull);
    }
    sp[tid] = (tid < NBA) ? posCnt[b * NBA + tid] : 0;
    sn[tid] = (tid < NBA) ? negCnt[b * NBA + tid] : 0;
    __syncthreads();

    // promote: unique winners adjust their containing block's counts
    if (tid < G_) {
        unsigned w = swin[tid];
        bool first = true;
        for (int j = 0; j < tid; ++j) if (swin[j] == w) first = false;
        if (first) {
            int8_t old = labels[(size_t)b * N_ + w];
            int blk = (int)(w / ABLK);
            if (old != 1) atomicAdd(&sp[blk], 1);
            if (old == 0) atomicAdd(&sn[blk], -1);
        }
    }
    __syncthreads();

    // scan 245 adjusted counts (Hillis-Steele)
    int vp = sp[tid], vn = sn[tid];
    for (int off = 1; off < 256; off <<= 1) {
        int tp = 0, tn = 0;
        if (tid >= off) { tp = sp[tid - off]; tn = sn[tid - off]; }
        __syncthreads();
        sp[tid] += tp; sn[tid] += tn;
        __syncthreads();
    }
    if (tid == blockIdx.x) {
        sBase[0] = sp[tid] - vp; sBase[1] = sn[tid] - vn;
        sBase[4] = vp; sBase[5] = vn;
    }
    if (tid == 255) { sBase[2] = sp[255]; sBase[3] = sn[255]; }
    __syncthreads();

    int posB = sBase[0], negB = sBase[1], totP = sBase[2], totN = sBase[3];
    int cPblk = sBase[4], cNblk = sBase[5];
    int npos = min(totP, RPN_BATCH / 2);
    int negQ = RPN_BATCH - npos;
    bool active = (cPblk > 0 && posB < RPN_BATCH / 2) || (cNblk > 0 && negB < negQ);
    if (!active && blockIdx.x != 0) return;

    int gbase = base + tid * 4;
    unsigned word = 0xFFFFFFFFu;
    if (gbase < N_)
        word = ((const unsigned*)labels)[(((size_t)b * N_ + base) >> 2) + tid];
    int lab[4];
#pragma unroll
    for (int j = 0; j < 4; ++j) lab[j] = (int)(char)((word >> (8 * j)) & 0xFF);
    // patch promoted winners (all 32, duplicates harmless)
    for (int g = 0; g < G_; ++g) {
        int d = (int)swin[g] - gbase;
        if (d >= 0 && d < 4) lab[d] = 1;
    }
    int cntP = 0, cntN = 0;
#pragma unroll
    for (int j = 0; j < 4; ++j) {
        if (gbase + j < N_) { cntP += (lab[j] == 1); cntN += (lab[j] == 0); }
    }

    int lane = tid & 63, wave = tid >> 6;
    int ip = cntP, inn = cntN;
    for (int off = 1; off < 64; off <<= 1) {
        int vpp = __shfl_up(ip, off), vnn = __shfl_up(inn, off);
        if (lane >= off) { ip += vpp; inn += vnn; }
    }
    if (lane == 63) { swP[wave] = ip; swN[wave] = inn; }
    __syncthreads();
    int bP = 0, bN = 0;
    for (int w = 0; w < wave; ++w) { bP += swP[w]; bN += swN[w]; }
    int pP = posB + bP + ip - cntP;
    int pN = negB + bN + inn - cntN;

    float bce = 0.f, regv = 0.f;
#pragma unroll
    for (int j = 0; j < 4; ++j) {
        int i = gbase + j;
        if (i >= N_) break;
        if (lab[j] == 1) {
            int r = pP++;
            if (r < RPN_BATCH / 2) {
                float l = rpn_scores[(size_t)b * N_ + i];
                bce += fmaxf(l, 0.f) - l + log1pf(expf(-fabsf(l)));
                float4 A = ((const float4*)anchors)[i];
                float areaA = (A.z - A.x) * (A.w - A.y);
                float best = -1.f; int am = 0;
                for (int g = 0; g < G_; ++g) {
                    float iou = iou_one(A.x, A.y, A.z, A.w, areaA,
                                        sg[g * 4], sg[g * 4 + 1], sg[g * 4 + 2], sg[g * 4 + 3]);
                    if (iou > best) { best = iou; am = g; }
                }
                float t0 = sg[am * 4], t1 = sg[am * 4 + 1], t2 = sg[am * 4 + 2], t3 = sg[am * 4 + 3];
                float wa = A.z - A.x, ha = A.w - A.y;
                float xa = A.x + 0.5f * wa, ya = A.y + 0.5f * ha;
                float wt = t2 - t0, ht = t3 - t1;
                float xt = t0 + 0.5f * wt, yt = t1 + 0.5f * ht;
                float4 D = ((const float4*)rpn_deltas)[(size_t)b * N_ + i];
                regv += smooth_l1(D.x - (xt - xa) / wa) + smooth_l1(D.y - (yt - ya) / ha) +
                        smooth_l1(D.z - logf(wt / wa + 1e-6f)) + smooth_l1(D.w - logf(ht / ha + 1e-6f));
            }
        } else if (lab[j] == 0) {
            int r = pN++;
            if (r < negQ) {
                float l = rpn_scores[(size_t)b * N_ + i];
                bce += fmaxf(l, 0.f) + log1pf(expf(-fabsf(l)));
            }
        }
    }
    for (int m = 32; m >= 1; m >>= 1) { bce += __shfl_xor(bce, m); regv += __shfl_xor(regv, m); }
    if (lane == 0) { sred[wave] = bce; sred[4 + wave] = regv; }
    __syncthreads();
    if (tid == 0) {
        float sb = sred[0] + sred[1] + sred[2] + sred[3];
        float sr = sred[4] + sred[5] + sred[6] + sred[7];
        int rnp = min(totP, RPN_BATCH / 2);
        int kneg = min(totN, RPN_BATCH - rnp);
        float denomC = fmaxf((float)(rnp + kneg), 1.f);
        float contrib = sb / denomC +
                        ((rnp > 0) ? sr / fmaxf((float)rnp * 4.f, 1.f) : 0.f);
        if (blockIdx.x == 0)
            contrib += detPart[b * DETB + 0] + detPart[b * DETB + 1] +
                       detPart[b * DETB + 2] + detPart[b * DETB + 3];
        if (contrib != 0.f || blockIdx.x == 0) atomicAdd(out, contrib);
    }
}

extern "C" void kernel_launch(void* const* d_in, const int* in_sizes, int n_in,
                              void* d_out, int out_size, void* d_ws, size_t ws_size,
                              hipStream_t stream) {
    const float* rpn_scores  = (const float*)d_in[0];
    const float* rpn_deltas  = (const float*)d_in[1];
    const float* cls_scores  = (const float*)d_in[2];
    const float* bbox_deltas = (const float*)d_in[3];
    const float* anchors     = (const float*)d_in[4];
    const float* proposals   = (const float*)d_in[5];
    const float* gt_boxes    = (const float*)d_in[6];
    const int*   gt_labels   = (const int*)d_in[7];
    float* out = (float*)d_out;

    char* ws = (char*)d_ws;
    size_t off = 0;
    auto alloc = [&](size_t bytes) -> char* {
        size_t o = (off + 255) & ~(size_t)255;
        off = o + bytes;
        return ws + o;
    };
    int8_t* labels = (int8_t*)alloc((size_t)B_ * N_);
    int* posCnt = (int*)alloc((size_t)B_ * NBA * 4);
    int* negCnt = (int*)alloc((size_t)B_ * NBA * 4);
    unsigned long long* gtWin = (unsigned long long*)alloc(B_ * G_ * 8);
    float* detPart = (float*)alloc(B_ * DETB * 4);

    hipMemsetAsync(gtWin, 0, B_ * G_ * 8, stream);
    rpn_assign_det<<<dim3(NBA + DETB, B_), 256, 0, stream>>>(
            anchors, gt_boxes, gt_labels, proposals, cls_scores, bbox_deltas,
            labels, posCnt, negCnt, gtWin, detPart, out, out_size);
    rpn_sample<<<dim3(NBA, B_), 256, 0, stream>>>(labels, rpn_scores, rpn_deltas,
                                                  anchors, gt_boxes, posCnt, negCnt,
                                                  gtWin, detPart, out);
}

// Round 3
// 141.496 us; speedup vs baseline: 1.1633x; 1.1633x over previous
//
#include <hip/hip_runtime.h>
#include <math.h>
#include <stdint.h>

#define B_ 4
#define N_ 250000
#define P_ 1000
#define G_ 32
#define C_ 81
#define RPN_BATCH 256
#define ROI_BATCH 128

#define ABLK 1024                                   // anchors per block
#define NBA ((N_ + ABLK - 1) / ABLK)                // 245
#define DETB 4                                      // det blocks per batch (32 ROIs each)

__device__ __forceinline__ float iou_one(float a0, float a1, float a2, float a3,
                                         float areaA,
                                         float b0, float b1, float b2, float b3) {
    float ltx = fmaxf(a0, b0), lty = fmaxf(a1, b1);
    float rbx = fminf(a2, b2), rby = fminf(a3, b3);
    float w = fmaxf(rbx - ltx, 0.f), h = fmaxf(rby - lty, 0.f);
    float inter = w * h;
    float areaB = (b2 - b0) * (b3 - b1);
    return inter / (areaA + areaB - inter + 1e-6f);
}

__device__ __forceinline__ unsigned long long shfl_xor_u64(unsigned long long v, int m) {
    unsigned lo = (unsigned)v, hi = (unsigned)(v >> 32);
    lo = __shfl_xor(lo, m);
    hi = __shfl_xor(hi, m);
    return ((unsigned long long)hi << 32) | lo;
}

__device__ __forceinline__ float smooth_l1(float x) {
    float ax = fabsf(x);
    return (ax < 1.f) ? 0.5f * x * x : ax - 0.5f;
}

// Kernel 1: fused RPN assign (blocks x < NBA) + detection loss (blocks x >= NBA).
// Per-(block,gt) winners written with plain coalesced stores to blockBest
// (NO global atomics — round-2's atomicMax cost +26 us from cross-XCD line
// ping-pong on 16 hot cache lines).
__global__ void __launch_bounds__(256, 4) rpn_assign_det(
        const float* __restrict__ anchors, const float* __restrict__ gt_boxes,
        const int* __restrict__ gt_labels, const float* __restrict__ proposals,
        const float* __restrict__ cls_scores, const float* __restrict__ bbox_deltas,
        int8_t* __restrict__ labels, int* __restrict__ posCnt, int* __restrict__ negCnt,
        unsigned long long* __restrict__ blockBest, float* __restrict__ detPart,
        float* __restrict__ out, int out_size) {
    int b = blockIdx.y, tid = threadIdx.x;
    int lane = tid & 63, wave = tid >> 6;

    if (blockIdx.x >= NBA) {
        // ---------------- detection-loss path (256 threads, 32 ROIs) ----------------
        int h = blockIdx.x - NBA;                 // which quarter of the 128 ROIs
        __shared__ float sgt[G_ * 4];
        __shared__ int sgl[G_];
        __shared__ short sassign[P_];
        __shared__ unsigned char sargm[P_];
        __shared__ int ssamp[ROI_BATCH];
        __shared__ int swd[4];
        __shared__ float sc[4], srg[4];
        if (tid < G_ * 4) sgt[tid] = gt_boxes[b * G_ * 4 + tid];
        if (tid < G_) sgl[tid] = gt_labels[b * G_ + tid];
        __syncthreads();

        // phase 1: assign proposals (4 per thread, blocked so scan order = index order)
        int myPos = 0;
        int labj[4];
#pragma unroll
        for (int j = 0; j < 4; ++j) {
            int p = tid * 4 + j;
            int labp = 0, am = 0;
            if (p < P_) {
                float4 A = ((const float4*)proposals)[b * P_ + p];
                float areaA = (A.z - A.x) * (A.w - A.y);
                float best = -1.f;
#pragma unroll 8
                for (int g = 0; g < G_; ++g) {
                    float iou = iou_one(A.x, A.y, A.z, A.w, areaA,
                                        sgt[g * 4], sgt[g * 4 + 1], sgt[g * 4 + 2], sgt[g * 4 + 3]);
                    if (iou > best) { best = iou; am = g; }
                }
                labp = (best >= 0.5f) ? sgl[am] : 0;
                sassign[p] = (short)labp;
                sargm[p] = (unsigned char)am;
                labj[j] = labp;
                myPos += (labp > 0);
            } else {
                labj[j] = -1;
            }
        }

        // phase 2: sampling ranks (wave scan + block scan over 4 waves)
        int inc = myPos;
        for (int off = 1; off < 64; off <<= 1) {
            int v = __shfl_up(inc, off);
            if (lane >= off) inc += v;
        }
        if (lane == 63) swd[wave] = inc;
        __syncthreads();
        int basew = 0, total = 0;
        for (int w = 0; w < 4; ++w) { if (w < wave) basew += swd[w]; total += swd[w]; }
        int pp = basew + inc - myPos;             // exclusive pos-prefix at proposal 4*tid
        int npos_kept = min(total, ROI_BATCH / 4);
        int nneg_total = P_ - total;
#pragma unroll
        for (int j = 0; j < 4; ++j) {
            int p = tid * 4 + j;
            if (labj[j] < 0) break;
            int slot;
            if (labj[j] > 0) {
                slot = (pp < ROI_BATCH / 4) ? pp : npos_kept + nneg_total + (pp - ROI_BATCH / 4);
                pp++;
            } else {
                slot = npos_kept + (p - pp);
            }
            if (slot < ROI_BATCH) ssamp[slot] = p;
        }
        int np_det = npos_kept + max(0, ROI_BATCH - npos_kept - nneg_total);
        __syncthreads();

        // phase 3: softmax CE straight from global (cls rows are L2-resident),
        // 2 rows per iteration for load-latency overlap; row[t] via shuffle.
        int rowBase = h * (ROI_BATCH / DETB) + wave * 8;
        float clsAcc = 0.f;
        for (int k = 0; k < 8; k += 2) {
            int s0 = ssamp[rowBase + k], s1 = ssamp[rowBase + k + 1];
            const float* r0 = cls_scores + ((size_t)(b * P_ + s0)) * C_;
            const float* r1 = cls_scores + ((size_t)(b * P_ + s1)) * C_;
            float a1 = r0[lane], b1 = r1[lane];
            float a2 = (lane < C_ - 64) ? r0[64 + lane] : -INFINITY;
            float b2 = (lane < C_ - 64) ? r1[64 + lane] : -INFINITY;
            float m0 = fmaxf(a1, a2), m1 = fmaxf(b1, b2);
            for (int mm = 32; mm >= 1; mm >>= 1) {
                m0 = fmaxf(m0, __shfl_xor(m0, mm));
                m1 = fmaxf(m1, __shfl_xor(m1, mm));
            }
            float e0 = expf(a1 - m0) + ((lane < C_ - 64) ? expf(a2 - m0) : 0.f);
            float e1 = expf(b1 - m1) + ((lane < C_ - 64) ? expf(b2 - m1) : 0.f);
            for (int mm = 32; mm >= 1; mm >>= 1) {
                e0 += __shfl_xor(e0, mm);
                e1 += __shfl_xor(e1, mm);
            }
            int t0 = sassign[s0], t1 = sassign[s1];
            int q0 = (t0 < 64) ? t0 : t0 - 64;
            int q1 = (t1 < 64) ? t1 : t1 - 64;
            float lo0 = __shfl(a1, q0), hi0 = __shfl(a2, q0);
            float lo1 = __shfl(b1, q1), hi1 = __shfl(b2, q1);
            float v0 = (t0 < 64) ? lo0 : hi0;
            float v1 = (t1 < 64) ? lo1 : hi1;
            if (lane == 0)
                clsAcc += -(v0 - m0 - logf(e0)) - (v1 - m1 - logf(e1));
        }

        // reg loss: one lane per ROI of this wave's 8 rows (parallel float4 loads)
        float regAcc = 0.f;
        if (lane < 8) {
            int r = rowBase + lane;
            int s = ssamp[r];
            int t = sassign[s];
            if (t > 0) {
                int g = sargm[s];
                float4 A = ((const float4*)proposals)[b * P_ + s];
                float t0g = sgt[g * 4], t1g = sgt[g * 4 + 1];
                float t2g = sgt[g * 4 + 2], t3g = sgt[g * 4 + 3];
                float wa = A.z - A.x, ha = A.w - A.y;
                float xa = A.x + 0.5f * wa, ya = A.y + 0.5f * ha;
                float wt = t2g - t0g, ht = t3g - t1g;
                float xt = t0g + 0.5f * wt, yt = t1g + 0.5f * ht;
                const float4 pd = *(const float4*)(bbox_deltas +
                        ((size_t)(b * P_ + s)) * (4 * C_) + 4 * t);
                regAcc = smooth_l1(pd.x - (xt - xa) / wa) + smooth_l1(pd.y - (yt - ya) / ha) +
                         smooth_l1(pd.z - logf(wt / wa + 1e-6f)) +
                         smooth_l1(pd.w - logf(ht / ha + 1e-6f));
            }
        }
        for (int mm = 32; mm >= 1; mm >>= 1) regAcc += __shfl_xor(regAcc, mm);
        if (lane == 0) { sc[wave] = clsAcc; srg[wave] = regAcc; }
        __syncthreads();
        if (tid == 0) {
            float cp = sc[0] + sc[1] + sc[2] + sc[3];
            float rp = srg[0] + srg[1] + srg[2] + srg[3];
            detPart[b * DETB + h] = cp / (float)ROI_BATCH +
                ((np_det > 0) ? rp / fmaxf((float)np_det * 4.f, 1.f) : 0.f);
        }
        return;
    }

    // ---------------- RPN assign path ----------------
    __shared__ float4 sA[ABLK];                 // 16 KB
    __shared__ unsigned char sPart[4][ABLK];    // 4 KB
    __shared__ int sCnt[8];

    int base = blockIdx.x * ABLK;

    if (blockIdx.x == 0 && b == 0) {
        for (int i = tid; i < out_size; i += 256) out[i] = 0.f;
    }

    for (int t = tid; t < ABLK; t += 256) {
        int ai = base + t;
        float4 v = make_float4(0.f, 0.f, 0.f, 0.f);
        if (ai < N_) v = ((const float4*)anchors)[ai];
        sA[t] = v;
    }
    __syncthreads();

    int waveu = __builtin_amdgcn_readfirstlane(wave);   // provably wave-uniform

    const float4* gt4 = (const float4*)gt_boxes + b * G_ + waveu * 8;
    float g0[8], g1[8], g2[8], g3[8], gae[8];
#pragma unroll
    for (int j = 0; j < 8; ++j) {
        float4 g = gt4[j];
        g0[j] = g.x; g1[j] = g.y; g2[j] = g.z; g3[j] = g.w;
        gae[j] = (g.z - g.x) * (g.w - g.y) + 1e-6f;
    }

    float bi[8], bd[8]; int bx[8];
#pragma unroll
    for (int j = 0; j < 8; ++j) { bi[j] = 0.f; bd[j] = 1.f; bx[j] = 0; }

    for (int k = 0; k < ABLK / 64; ++k) {
        int a = k * 64 + lane;
        float4 A = sA[a];
        float areaA = (A.z - A.x) * (A.w - A.y);
        int gidx = base + a;
        float acc03 = 1e30f, acc07 = 1e30f;
#pragma unroll
        for (int j = 0; j < 8; ++j) {
            float ltx = fmaxf(A.x, g0[j]), lty = fmaxf(A.y, g1[j]);
            float rbx = fminf(A.z, g2[j]), rby = fminf(A.w, g3[j]);
            float w = fmaxf(rbx - ltx, 0.f), h = fmaxf(rby - lty, 0.f);
            float inter = w * h;
            float d = (areaA + gae[j]) - inter;
            acc03 = fminf(acc03, fmaf(0.3f, d, -inter)); // >0 => iou<0.3
            acc07 = fminf(acc07, fmaf(0.7f, d, -inter)); // <0 => iou>0.7
            float p1 = inter * bd[j], p2 = bi[j] * d;
            if (p1 > p2) { bi[j] = inter; bd[j] = d; bx[j] = gidx; }
        }
        sPart[wave][a] = (unsigned char)(((acc07 < 0.f) ? 2 : 0) | ((acc03 > 0.f) ? 1 : 0));
    }

#pragma unroll
    for (int j = 0; j < 8; ++j) {
        float i_ = bi[j], d_ = bd[j]; int x_ = bx[j];
        for (int m = 32; m >= 1; m >>= 1) {
            float oi = __shfl_xor(i_, m), od = __shfl_xor(d_, m);
            int ox = __shfl_xor(x_, m);
            float pa = oi * d_, pb = i_ * od;
            bool take = (pa > pb) || (pa == pb && ox < x_);
            if (take) { i_ = oi; d_ = od; x_ = ox; }
        }
        if (lane == 0) {
            float iou = i_ / d_;
            unsigned long long pk =
                (((unsigned long long)__float_as_uint(iou)) << 32) |
                (unsigned)(0xFFFFFFFFu - (unsigned)x_);
            blockBest[((size_t)b * G_ + wave * 8 + j) * NBA + blockIdx.x] = pk;
        }
    }
    __syncthreads();

    unsigned u0 = ((const unsigned*)&sPart[0][0])[tid];
    unsigned u1 = ((const unsigned*)&sPart[1][0])[tid];
    unsigned u2 = ((const unsigned*)&sPart[2][0])[tid];
    unsigned u3 = ((const unsigned*)&sPart[3][0])[tid];
    unsigned andb = u0 & u1 & u2 & u3;
    unsigned orb  = u0 | u1 | u2 | u3;
    int gbase = base + tid * 4;
    unsigned outw = 0; int cp = 0, cn = 0;
#pragma unroll
    for (int j = 0; j < 4; ++j) {
        int above = (orb >> (8 * j + 1)) & 1;
        int below = (andb >> (8 * j)) & 1;
        int lab = above ? 1 : (below ? 0 : -1);
        if (gbase + j < N_) { cp += (lab == 1); cn += (lab == 0); }
        outw |= ((unsigned)(unsigned char)(char)lab) << (8 * j);
    }
    if (gbase < N_)
        ((unsigned*)labels)[(((size_t)b * N_ + base) >> 2) + tid] = outw;

    for (int m = 32; m >= 1; m >>= 1) { cp += __shfl_xor(cp, m); cn += __shfl_xor(cn, m); }
    if (lane == 0) { sCnt[wave] = cp; sCnt[4 + wave] = cn; }
    __syncthreads();
    if (tid == 0) {
        posCnt[b * NBA + blockIdx.x] = sCnt[0] + sCnt[1] + sCnt[2] + sCnt[3];
        negCnt[b * NBA + blockIdx.x] = sCnt[4] + sCnt[5] + sCnt[6] + sCnt[7];
    }
}

// Kernel 2: each block re-derives winners (L2-hit reduction over blockBest),
// promote + register wave-scan locally, early-exits if it holds no sampled
// anchors, else computes BCE/reg partials, pre-divided, atomically into out.
__global__ void __launch_bounds__(256) rpn_sample(
        const int8_t* __restrict__ labels, const float* __restrict__ rpn_scores,
        const float* __restrict__ rpn_deltas, const float* __restrict__ anchors,
        const float* __restrict__ gt_boxes,
        const int* __restrict__ posCnt, const int* __restrict__ negCnt,
        const unsigned long long* __restrict__ blockBest,
        const float* __restrict__ detPart, float* __restrict__ out) {
    int b = blockIdx.y, tid = threadIdx.x;
    int base = blockIdx.x * ABLK;
    int lane = tid & 63, wave = tid >> 6;
    __shared__ float sg[G_ * 4];
    __shared__ int sp[256], sn[256];
    __shared__ unsigned swin[G_];
    __shared__ int sBase[6];     // posBase, negBase, totP, totN, cntP_blk, cntN_blk
    __shared__ int sWT[8];       // wave totals (pos 0..3, neg 4..7)
    __shared__ int swP[4], swN[4];
    __shared__ float sred[8];

    if (tid < G_ * 4) sg[tid] = gt_boxes[b * G_ * 4 + tid];
    sp[tid] = (tid < NBA) ? posCnt[b * NBA + tid] : 0;
    sn[tid] = (tid < NBA) ? negCnt[b * NBA + tid] : 0;

    // per-gt winner reduction: 32 gts x 8 threads over 245 block winners (L2-hit)
    {
        int g = tid >> 3, sub = tid & 7;
        unsigned long long v = 0;
        for (int j = sub; j < NBA; j += 8) {
            unsigned long long x = blockBest[((size_t)b * G_ + g) * NBA + j];
            if (x > v) v = x;
        }
        for (int m = 4; m >= 1; m >>= 1) {
            unsigned long long o = shfl_xor_u64(v, m);
            if (o > v) v = o;
        }
        if (sub == 0) swin[g] = 0xFFFFFFFFu - (unsigned)(v & 0xFFFFFFFFull);
    }
    __syncthreads();

    // promote: unique winners adjust their containing block's counts
    if (tid < G_) {
        unsigned w = swin[tid];
        bool first = true;
        for (int j = 0; j < tid; ++j) if (swin[j] == w) first = false;
        if (first) {
            int8_t old = labels[(size_t)b * N_ + w];
            int blk = (int)(w / ABLK);
            if (old != 1) atomicAdd(&sp[blk], 1);
            if (old == 0) atomicAdd(&sn[blk], -1);
        }
    }
    __syncthreads();

    // register wave-scan over the 256 count slots (2 barriers, not 17)
    int vp = sp[tid], vn = sn[tid];
    int ipp = vp, inn2 = vn;
    for (int off = 1; off < 64; off <<= 1) {
        int a = __shfl_up(ipp, off), c = __shfl_up(inn2, off);
        if (lane >= off) { ipp += a; inn2 += c; }
    }
    if (lane == 63) { sWT[wave] = ipp; sWT[4 + wave] = inn2; }
    __syncthreads();
    int preP = 0, preN = 0;
    for (int w = 0; w < wave; ++w) { preP += sWT[w]; preN += sWT[4 + w]; }
    int inclP = preP + ipp, inclN = preN + inn2;
    if (tid == blockIdx.x) {
        sBase[0] = inclP - vp; sBase[1] = inclN - vn;
        sBase[4] = vp; sBase[5] = vn;
    }
    if (tid == 255) { sBase[2] = inclP; sBase[3] = inclN; }
    __syncthreads();

    int posB = sBase[0], negB = sBase[1], totP = sBase[2], totN = sBase[3];
    int cPblk = sBase[4], cNblk = sBase[5];
    int npos = min(totP, RPN_BATCH / 2);
    int negQ = RPN_BATCH - npos;
    bool active = (cPblk > 0 && posB < RPN_BATCH / 2) || (cNblk > 0 && negB < negQ);
    if (!active && blockIdx.x != 0) return;

    int gbase = base + tid * 4;
    unsigned word = 0xFFFFFFFFu;
    if (gbase < N_)
        word = ((const unsigned*)labels)[(((size_t)b * N_ + base) >> 2) + tid];
    int lab[4];
#pragma unroll
    for (int j = 0; j < 4; ++j) lab[j] = (int)(char)((word >> (8 * j)) & 0xFF);
    // patch promoted winners (all 32, duplicates harmless)
    for (int g = 0; g < G_; ++g) {
        int d = (int)swin[g] - gbase;
        if (d >= 0 && d < 4) lab[d] = 1;
    }
    int cntP = 0, cntN = 0;
#pragma unroll
    for (int j = 0; j < 4; ++j) {
        if (gbase + j < N_) { cntP += (lab[j] == 1); cntN += (lab[j] == 0); }
    }

    int ip = cntP, inn = cntN;
    for (int off = 1; off < 64; off <<= 1) {
        int vpp = __shfl_up(ip, off), vnn = __shfl_up(inn, off);
        if (lane >= off) { ip += vpp; inn += vnn; }
    }
    if (lane == 63) { swP[wave] = ip; swN[wave] = inn; }
    __syncthreads();
    int bP = 0, bN = 0;
    for (int w = 0; w < wave; ++w) { bP += swP[w]; bN += swN[w]; }
    int pP = posB + bP + ip - cntP;
    int pN = negB + bN + inn - cntN;

    float bce = 0.f, regv = 0.f;
#pragma unroll
    for (int j = 0; j < 4; ++j) {
        int i = gbase + j;
        if (i >= N_) break;
        if (lab[j] == 1) {
            int r = pP++;
            if (r < RPN_BATCH / 2) {
                float l = rpn_scores[(size_t)b * N_ + i];
                bce += fmaxf(l, 0.f) - l + log1pf(expf(-fabsf(l)));
                float4 A = ((const float4*)anchors)[i];
                float areaA = (A.z - A.x) * (A.w - A.y);
                float best = -1.f; int am = 0;
                for (int g = 0; g < G_; ++g) {
                    float iou = iou_one(A.x, A.y, A.z, A.w, areaA,
                                        sg[g * 4], sg[g * 4 + 1], sg[g * 4 + 2], sg[g * 4 + 3]);
                    if (iou > best) { best = iou; am = g; }
                }
                float t0 = sg[am * 4], t1 = sg[am * 4 + 1], t2 = sg[am * 4 + 2], t3 = sg[am * 4 + 3];
                float wa = A.z - A.x, ha = A.w - A.y;
                float xa = A.x + 0.5f * wa, ya = A.y + 0.5f * ha;
                float wt = t2 - t0, ht = t3 - t1;
                float xt = t0 + 0.5f * wt, yt = t1 + 0.5f * ht;
                float4 D = ((const float4*)rpn_deltas)[(size_t)b * N_ + i];
                regv += smooth_l1(D.x - (xt - xa) / wa) + smooth_l1(D.y - (yt - ya) / ha) +
                        smooth_l1(D.z - logf(wt / wa + 1e-6f)) + smooth_l1(D.w - logf(ht / ha + 1e-6f));
            }
        } else if (lab[j] == 0) {
            int r = pN++;
            if (r < negQ) {
                float l = rpn_scores[(size_t)b * N_ + i];
                bce += fmaxf(l, 0.f) + log1pf(expf(-fabsf(l)));
            }
        }
    }
    for (int m = 32; m >= 1; m >>= 1) { bce += __shfl_xor(bce, m); regv += __shfl_xor(regv, m); }
    if (lane == 0) { sred[wave] = bce; sred[4 + wave] = regv; }
    __syncthreads();
    if (tid == 0) {
        float sb = sred[0] + sred[1] + sred[2] + sred[3];
        float sr = sred[4] + sred[5] + sred[6] + sred[7];
        int rnp = min(totP, RPN_BATCH / 2);
        int kneg = min(totN, RPN_BATCH - rnp);
        float denomC = fmaxf((float)(rnp + kneg), 1.f);
        float contrib = sb / denomC +
                        ((rnp > 0) ? sr / fmaxf((float)rnp * 4.f, 1.f) : 0.f);
        if (blockIdx.x == 0)
            contrib += detPart[b * DETB + 0] + detPart[b * DETB + 1] +
                       detPart[b * DETB + 2] + detPart[b * DETB + 3];
        if (contrib != 0.f || blockIdx.x == 0) atomicAdd(out, contrib);
    }
}

extern "C" void kernel_launch(void* const* d_in, const int* in_sizes, int n_in,
                              void* d_out, int out_size, void* d_ws, size_t ws_size,
                              hipStream_t stream) {
    const float* rpn_scores  = (const float*)d_in[0];
    const float* rpn_deltas  = (const float*)d_in[1];
    const float* cls_scores  = (const float*)d_in[2];
    const float* bbox_deltas = (const float*)d_in[3];
    const float* anchors     = (const float*)d_in[4];
    const float* proposals   = (const float*)d_in[5];
    const float* gt_boxes    = (const float*)d_in[6];
    const int*   gt_labels   = (const int*)d_in[7];
    float* out = (float*)d_out;

    char* ws = (char*)d_ws;
    size_t off = 0;
    auto alloc = [&](size_t bytes) -> char* {
        size_t o = (off + 255) & ~(size_t)255;
        off = o + bytes;
        return ws + o;
    };
    int8_t* labels = (int8_t*)alloc((size_t)B_ * N_);
    int* posCnt = (int*)alloc((size_t)B_ * NBA * 4);
    int* negCnt = (int*)alloc((size_t)B_ * NBA * 4);
    unsigned long long* blockBest = (unsigned long long*)alloc((size_t)B_ * G_ * NBA * 8);
    float* detPart = (float*)alloc(B_ * DETB * 4);

    rpn_assign_det<<<dim3(NBA + DETB, B_), 256, 0, stream>>>(
            anchors, gt_boxes, gt_labels, proposals, cls_scores, bbox_deltas,
            labels, posCnt, negCnt, blockBest, detPart, out, out_size);
    rpn_sample<<<dim3(NBA, B_), 256, 0, stream>>>(labels, rpn_scores, rpn_deltas,
                                                  anchors, gt_boxes, posCnt, negCnt,
                                                  blockBest, detPart, out);
}

// Round 4
// 135.974 us; speedup vs baseline: 1.2106x; 1.0406x over previous
//
#include <hip/hip_runtime.h>
#include <math.h>
#include <stdint.h>

#define B_ 4
#define N_ 250000
#define P_ 1000
#define G_ 32
#define C_ 81
#define RPN_BATCH 256
#define ROI_BATCH 128

#define ABLK 1024                                   // anchors per block
#define NBA ((N_ + ABLK - 1) / ABLK)                // 245
#define DETB 4                                      // det blocks per batch (32 ROIs each)

__device__ __forceinline__ float iou_one(float a0, float a1, float a2, float a3,
                                         float areaA,
                                         float b0, float b1, float b2, float b3) {
    float ltx = fmaxf(a0, b0), lty = fmaxf(a1, b1);
    float rbx = fminf(a2, b2), rby = fminf(a3, b3);
    float w = fmaxf(rbx - ltx, 0.f), h = fmaxf(rby - lty, 0.f);
    float inter = w * h;
    float areaB = (b2 - b0) * (b3 - b1);
    return inter / (areaA + areaB - inter + 1e-6f);
}

__device__ __forceinline__ unsigned long long shfl_xor_u64(unsigned long long v, int m) {
    unsigned lo = (unsigned)v, hi = (unsigned)(v >> 32);
    lo = __shfl_xor(lo, m);
    hi = __shfl_xor(hi, m);
    return ((unsigned long long)hi << 32) | lo;
}

__device__ __forceinline__ float smooth_l1(float x) {
    float ax = fabsf(x);
    return (ax < 1.f) ? 0.5f * x * x : ax - 0.5f;
}

// Kernel 1 (512 threads, 8 waves): fused RPN assign (blocks x < NBA) + det loss
// (blocks x >= NBA). 512 threads raises residency to ~31 waves/CU (was ~16):
// grid is only ~3.9 blocks/CU, so occupancy was grid-limited, not resource-
// limited. Each wave owns 4 gts; per-anchor lane mapping unchanged (results
// bit-identical to the 256-thread version).
__global__ void __launch_bounds__(512, 8) rpn_assign_det(
        const float* __restrict__ anchors, const float* __restrict__ gt_boxes,
        const int* __restrict__ gt_labels, const float* __restrict__ proposals,
        const float* __restrict__ cls_scores, const float* __restrict__ bbox_deltas,
        int8_t* __restrict__ labels, int* __restrict__ posCnt, int* __restrict__ negCnt,
        unsigned long long* __restrict__ blockBest, float* __restrict__ detPart,
        float* __restrict__ out, int out_size) {
    int b = blockIdx.y, tid = threadIdx.x;
    int lane = tid & 63, wave = tid >> 6;          // 8 waves

    if (blockIdx.x >= NBA) {
        // ---------------- detection-loss path (512 threads, 32 ROIs) ----------------
        int h = blockIdx.x - NBA;                 // which quarter of the 128 ROIs
        __shared__ float sgt[G_ * 4];
        __shared__ int sgl[G_];
        __shared__ short sassign[P_];
        __shared__ unsigned char sargm[P_];
        __shared__ int ssamp[ROI_BATCH];
        __shared__ int swd[8];
        __shared__ float sc[8], srg[8];
        if (tid < G_ * 4) sgt[tid] = gt_boxes[b * G_ * 4 + tid];
        if (tid < G_) sgl[tid] = gt_labels[b * G_ + tid];
        __syncthreads();

        // phase 1: assign proposals (2 per thread, blocked so scan order = index order)
        int myPos = 0;
        int labj[2];
#pragma unroll
        for (int j = 0; j < 2; ++j) {
            int p = tid * 2 + j;
            int labp = 0, am = 0;
            if (p < P_) {
                float4 A = ((const float4*)proposals)[b * P_ + p];
                float areaA = (A.z - A.x) * (A.w - A.y);
                float best = -1.f;
#pragma unroll 8
                for (int g = 0; g < G_; ++g) {
                    float iou = iou_one(A.x, A.y, A.z, A.w, areaA,
                                        sgt[g * 4], sgt[g * 4 + 1], sgt[g * 4 + 2], sgt[g * 4 + 3]);
                    if (iou > best) { best = iou; am = g; }
                }
                labp = (best >= 0.5f) ? sgl[am] : 0;
                sassign[p] = (short)labp;
                sargm[p] = (unsigned char)am;
                labj[j] = labp;
                myPos += (labp > 0);
            } else {
                labj[j] = -1;
            }
        }

        // phase 2: sampling ranks (wave scan + block scan over 8 waves)
        int inc = myPos;
        for (int off = 1; off < 64; off <<= 1) {
            int v = __shfl_up(inc, off);
            if (lane >= off) inc += v;
        }
        if (lane == 63) swd[wave] = inc;
        __syncthreads();
        int basew = 0, total = 0;
        for (int w = 0; w < 8; ++w) { if (w < wave) basew += swd[w]; total += swd[w]; }
        int pp = basew + inc - myPos;             // exclusive pos-prefix at proposal 2*tid
        int npos_kept = min(total, ROI_BATCH / 4);
        int nneg_total = P_ - total;
#pragma unroll
        for (int j = 0; j < 2; ++j) {
            int p = tid * 2 + j;
            if (labj[j] < 0) break;
            int slot;
            if (labj[j] > 0) {
                slot = (pp < ROI_BATCH / 4) ? pp : npos_kept + nneg_total + (pp - ROI_BATCH / 4);
                pp++;
            } else {
                slot = npos_kept + (p - pp);
            }
            if (slot < ROI_BATCH) ssamp[slot] = p;
        }
        int np_det = npos_kept + max(0, ROI_BATCH - npos_kept - nneg_total);
        __syncthreads();

        // phase 3: softmax CE straight from global (cls rows are L2-resident),
        // 2 rows per iteration for load-latency overlap; row[t] via shuffle.
        int rowBase = h * (ROI_BATCH / DETB) + wave * 4;   // 8 waves x 4 rows
        float clsAcc = 0.f;
        for (int k = 0; k < 4; k += 2) {
            int s0 = ssamp[rowBase + k], s1 = ssamp[rowBase + k + 1];
            const float* r0 = cls_scores + ((size_t)(b * P_ + s0)) * C_;
            const float* r1 = cls_scores + ((size_t)(b * P_ + s1)) * C_;
            float a1 = r0[lane], b1 = r1[lane];
            float a2 = (lane < C_ - 64) ? r0[64 + lane] : -INFINITY;
            float b2 = (lane < C_ - 64) ? r1[64 + lane] : -INFINITY;
            float m0 = fmaxf(a1, a2), m1 = fmaxf(b1, b2);
            for (int mm = 32; mm >= 1; mm >>= 1) {
                m0 = fmaxf(m0, __shfl_xor(m0, mm));
                m1 = fmaxf(m1, __shfl_xor(m1, mm));
            }
            float e0 = expf(a1 - m0) + ((lane < C_ - 64) ? expf(a2 - m0) : 0.f);
            float e1 = expf(b1 - m1) + ((lane < C_ - 64) ? expf(b2 - m1) : 0.f);
            for (int mm = 32; mm >= 1; mm >>= 1) {
                e0 += __shfl_xor(e0, mm);
                e1 += __shfl_xor(e1, mm);
            }
            int t0 = sassign[s0], t1 = sassign[s1];
            int q0 = (t0 < 64) ? t0 : t0 - 64;
            int q1 = (t1 < 64) ? t1 : t1 - 64;
            float lo0 = __shfl(a1, q0), hi0 = __shfl(a2, q0);
            float lo1 = __shfl(b1, q1), hi1 = __shfl(b2, q1);
            float v0 = (t0 < 64) ? lo0 : hi0;
            float v1 = (t1 < 64) ? lo1 : hi1;
            if (lane == 0)
                clsAcc += -(v0 - m0 - logf(e0)) - (v1 - m1 - logf(e1));
        }

        // reg loss: one lane per ROI of this wave's 4 rows (parallel float4 loads)
        float regAcc = 0.f;
        if (lane < 4) {
            int r = rowBase + lane;
            int s = ssamp[r];
            int t = sassign[s];
            if (t > 0) {
                int g = sargm[s];
                float4 A = ((const float4*)proposals)[b * P_ + s];
                float t0g = sgt[g * 4], t1g = sgt[g * 4 + 1];
                float t2g = sgt[g * 4 + 2], t3g = sgt[g * 4 + 3];
                float wa = A.z - A.x, ha = A.w - A.y;
                float xa = A.x + 0.5f * wa, ya = A.y + 0.5f * ha;
                float wt = t2g - t0g, ht = t3g - t1g;
                float xt = t0g + 0.5f * wt, yt = t1g + 0.5f * ht;
                const float4 pd = *(const float4*)(bbox_deltas +
                        ((size_t)(b * P_ + s)) * (4 * C_) + 4 * t);
                regAcc = smooth_l1(pd.x - (xt - xa) / wa) + smooth_l1(pd.y - (yt - ya) / ha) +
                         smooth_l1(pd.z - logf(wt / wa + 1e-6f)) +
                         smooth_l1(pd.w - logf(ht / ha + 1e-6f));
            }
        }
        for (int mm = 32; mm >= 1; mm >>= 1) regAcc += __shfl_xor(regAcc, mm);
        if (lane == 0) { sc[wave] = clsAcc; srg[wave] = regAcc; }
        __syncthreads();
        if (tid == 0) {
            float cp = 0.f, rp = 0.f;
            for (int w = 0; w < 8; ++w) { cp += sc[w]; rp += srg[w]; }
            detPart[b * DETB + h] = cp / (float)ROI_BATCH +
                ((np_det > 0) ? rp / fmaxf((float)np_det * 4.f, 1.f) : 0.f);
        }
        return;
    }

    // ---------------- RPN assign path ----------------
    __shared__ float4 sA[ABLK];                 // 16 KB
    __shared__ unsigned char sPart[8][ABLK];    // 8 KB
    __shared__ int sCnt[16];

    int base = blockIdx.x * ABLK;

    if (blockIdx.x == 0 && b == 0) {
        for (int i = tid; i < out_size; i += 512) out[i] = 0.f;
    }

    for (int t = tid; t < ABLK; t += 512) {
        int ai = base + t;
        float4 v = make_float4(0.f, 0.f, 0.f, 0.f);
        if (ai < N_) v = ((const float4*)anchors)[ai];
        sA[t] = v;
    }
    __syncthreads();

    int waveu = __builtin_amdgcn_readfirstlane(wave);   // provably wave-uniform

    const float4* gt4 = (const float4*)gt_boxes + b * G_ + waveu * 4;
    float g0[4], g1[4], g2[4], g3[4], gae[4];
#pragma unroll
    for (int j = 0; j < 4; ++j) {
        float4 g = gt4[j];
        g0[j] = g.x; g1[j] = g.y; g2[j] = g.z; g3[j] = g.w;
        gae[j] = (g.z - g.x) * (g.w - g.y) + 1e-6f;
    }

    float bi[4], bd[4]; int bx[4];
#pragma unroll
    for (int j = 0; j < 4; ++j) { bi[j] = 0.f; bd[j] = 1.f; bx[j] = 0; }

    for (int k = 0; k < ABLK / 64; ++k) {
        int a = k * 64 + lane;
        float4 A = sA[a];
        float areaA = (A.z - A.x) * (A.w - A.y);
        int gidx = base + a;
        float acc03 = 1e30f, acc07 = 1e30f;
#pragma unroll
        for (int j = 0; j < 4; ++j) {
            float ltx = fmaxf(A.x, g0[j]), lty = fmaxf(A.y, g1[j]);
            float rbx = fminf(A.z, g2[j]), rby = fminf(A.w, g3[j]);
            float w = fmaxf(rbx - ltx, 0.f), h = fmaxf(rby - lty, 0.f);
            float inter = w * h;
            float d = (areaA + gae[j]) - inter;
            acc03 = fminf(acc03, fmaf(0.3f, d, -inter)); // >0 => iou<0.3
            acc07 = fminf(acc07, fmaf(0.7f, d, -inter)); // <0 => iou>0.7
            float p1 = inter * bd[j], p2 = bi[j] * d;
            if (p1 > p2) { bi[j] = inter; bd[j] = d; bx[j] = gidx; }
        }
        sPart[wave][a] = (unsigned char)(((acc07 < 0.f) ? 2 : 0) | ((acc03 > 0.f) ? 1 : 0));
    }

#pragma unroll
    for (int j = 0; j < 4; ++j) {
        float i_ = bi[j], d_ = bd[j]; int x_ = bx[j];
        for (int m = 32; m >= 1; m >>= 1) {
            float oi = __shfl_xor(i_, m), od = __shfl_xor(d_, m);
            int ox = __shfl_xor(x_, m);
            float pa = oi * d_, pb = i_ * od;
            bool take = (pa > pb) || (pa == pb && ox < x_);
            if (take) { i_ = oi; d_ = od; x_ = ox; }
        }
        if (lane == 0) {
            float iou = i_ / d_;
            unsigned long long pk =
                (((unsigned long long)__float_as_uint(iou)) << 32) |
                (unsigned)(0xFFFFFFFFu - (unsigned)x_);
            blockBest[((size_t)b * G_ + wave * 4 + j) * NBA + blockIdx.x] = pk;
        }
    }
    __syncthreads();

    int cp = 0, cn = 0;
    if (tid < ABLK / 4) {
        unsigned andb = 0xFFFFFFFFu, orb = 0u;
#pragma unroll
        for (int w = 0; w < 8; ++w) {
            unsigned u = ((const unsigned*)&sPart[w][0])[tid];
            andb &= u; orb |= u;
        }
        int gbase = base + tid * 4;
        unsigned outw = 0;
#pragma unroll
        for (int j = 0; j < 4; ++j) {
            int above = (orb >> (8 * j + 1)) & 1;
            int below = (andb >> (8 * j)) & 1;
            int lab = above ? 1 : (below ? 0 : -1);
            if (gbase + j < N_) { cp += (lab == 1); cn += (lab == 0); }
            outw |= ((unsigned)(unsigned char)(char)lab) << (8 * j);
        }
        if (gbase < N_)
            ((unsigned*)labels)[(((size_t)b * N_ + base) >> 2) + tid] = outw;
    }

    for (int m = 32; m >= 1; m >>= 1) { cp += __shfl_xor(cp, m); cn += __shfl_xor(cn, m); }
    if (lane == 0) { sCnt[wave] = cp; sCnt[8 + wave] = cn; }
    __syncthreads();
    if (tid == 0) {
        int tp = 0, tn = 0;
        for (int w = 0; w < 8; ++w) { tp += sCnt[w]; tn += sCnt[8 + w]; }
        posCnt[b * NBA + blockIdx.x] = tp;
        negCnt[b * NBA + blockIdx.x] = tn;
    }
}

// Kernel 2: each block re-derives winners (L2-hit reduction over blockBest),
// promote + register wave-scan locally, early-exits if it holds no sampled
// anchors, else computes BCE/reg partials, pre-divided, atomically into out.
__global__ void __launch_bounds__(256) rpn_sample(
        const int8_t* __restrict__ labels, const float* __restrict__ rpn_scores,
        const float* __restrict__ rpn_deltas, const float* __restrict__ anchors,
        const float* __restrict__ gt_boxes,
        const int* __restrict__ posCnt, const int* __restrict__ negCnt,
        const unsigned long long* __restrict__ blockBest,
        const float* __restrict__ detPart, float* __restrict__ out) {
    int b = blockIdx.y, tid = threadIdx.x;
    int base = blockIdx.x * ABLK;
    int lane = tid & 63, wave = tid >> 6;
    __shared__ float sg[G_ * 4];
    __shared__ int sp[256], sn[256];
    __shared__ unsigned swin[G_];
    __shared__ int sBase[6];     // posBase, negBase, totP, totN, cntP_blk, cntN_blk
    __shared__ int sWT[8];       // wave totals (pos 0..3, neg 4..7)
    __shared__ int swP[4], swN[4];
    __shared__ float sred[8];

    if (tid < G_ * 4) sg[tid] = gt_boxes[b * G_ * 4 + tid];
    sp[tid] = (tid < NBA) ? posCnt[b * NBA + tid] : 0;
    sn[tid] = (tid < NBA) ? negCnt[b * NBA + tid] : 0;

    // per-gt winner reduction: 32 gts x 8 threads over 245 block winners (L2-hit)
    {
        int g = tid >> 3, sub = tid & 7;
        unsigned long long v = 0;
        for (int j = sub; j < NBA; j += 8) {
            unsigned long long x = blockBest[((size_t)b * G_ + g) * NBA + j];
            if (x > v) v = x;
        }
        for (int m = 4; m >= 1; m >>= 1) {
            unsigned long long o = shfl_xor_u64(v, m);
            if (o > v) v = o;
        }
        if (sub == 0) swin[g] = 0xFFFFFFFFu - (unsigned)(v & 0xFFFFFFFFull);
    }
    __syncthreads();

    // promote: unique winners adjust their containing block's counts
    if (tid < G_) {
        unsigned w = swin[tid];
        bool first = true;
        for (int j = 0; j < tid; ++j) if (swin[j] == w) first = false;
        if (first) {
            int8_t old = labels[(size_t)b * N_ + w];
            int blk = (int)(w / ABLK);
            if (old != 1) atomicAdd(&sp[blk], 1);
            if (old == 0) atomicAdd(&sn[blk], -1);
        }
    }
    __syncthreads();

    // register wave-scan over the 256 count slots (2 barriers, not 17)
    int vp = sp[tid], vn = sn[tid];
    int ipp = vp, inn2 = vn;
    for (int off = 1; off < 64; off <<= 1) {
        int a = __shfl_up(ipp, off), c = __shfl_up(inn2, off);
        if (lane >= off) { ipp += a; inn2 += c; }
    }
    if (lane == 63) { sWT[wave] = ipp; sWT[4 + wave] = inn2; }
    __syncthreads();
    int preP = 0, preN = 0;
    for (int w = 0; w < wave; ++w) { preP += sWT[w]; preN += sWT[4 + w]; }
    int inclP = preP + ipp, inclN = preN + inn2;
    if (tid == blockIdx.x) {
        sBase[0] = inclP - vp; sBase[1] = inclN - vn;
        sBase[4] = vp; sBase[5] = vn;
    }
    if (tid == 255) { sBase[2] = inclP; sBase[3] = inclN; }
    __syncthreads();

    int posB = sBase[0], negB = sBase[1], totP = sBase[2], totN = sBase[3];
    int cPblk = sBase[4], cNblk = sBase[5];
    int npos = min(totP, RPN_BATCH / 2);
    int negQ = RPN_BATCH - npos;
    bool active = (cPblk > 0 && posB < RPN_BATCH / 2) || (cNblk > 0 && negB < negQ);
    if (!active && blockIdx.x != 0) return;

    int gbase = base + tid * 4;
    unsigned word = 0xFFFFFFFFu;
    if (gbase < N_)
        word = ((const unsigned*)labels)[(((size_t)b * N_ + base) >> 2) + tid];
    int lab[4];
#pragma unroll
    for (int j = 0; j < 4; ++j) lab[j] = (int)(char)((word >> (8 * j)) & 0xFF);
    // patch promoted winners (all 32, duplicates harmless)
    for (int g = 0; g < G_; ++g) {
        int d = (int)swin[g] - gbase;
        if (d >= 0 && d < 4) lab[d] = 1;
    }
    int cntP = 0, cntN = 0;
#pragma unroll
    for (int j = 0; j < 4; ++j) {
        if (gbase + j < N_) { cntP += (lab[j] == 1); cntN += (lab[j] == 0); }
    }

    int ip = cntP, inn = cntN;
    for (int off = 1; off < 64; off <<= 1) {
        int vpp = __shfl_up(ip, off), vnn = __shfl_up(inn, off);
        if (lane >= off) { ip += vpp; inn += vnn; }
    }
    if (lane == 63) { swP[wave] = ip; swN[wave] = inn; }
    __syncthreads();
    int bP = 0, bN = 0;
    for (int w = 0; w < wave; ++w) { bP += swP[w]; bN += swN[w]; }
    int pP = posB + bP + ip - cntP;
    int pN = negB + bN + inn - cntN;

    float bce = 0.f, regv = 0.f;
#pragma unroll
    for (int j = 0; j < 4; ++j) {
        int i = gbase + j;
        if (i >= N_) break;
        if (lab[j] == 1) {
            int r = pP++;
            if (r < RPN_BATCH / 2) {
                float l = rpn_scores[(size_t)b * N_ + i];
                bce += fmaxf(l, 0.f) - l + log1pf(expf(-fabsf(l)));
                float4 A = ((const float4*)anchors)[i];
                float areaA = (A.z - A.x) * (A.w - A.y);
                float best = -1.f; int am = 0;
                for (int g = 0; g < G_; ++g) {
                    float iou = iou_one(A.x, A.y, A.z, A.w, areaA,
                                        sg[g * 4], sg[g * 4 + 1], sg[g * 4 + 2], sg[g * 4 + 3]);
                    if (iou > best) { best = iou; am = g; }
                }
                float t0 = sg[am * 4], t1 = sg[am * 4 + 1], t2 = sg[am * 4 + 2], t3 = sg[am * 4 + 3];
                float wa = A.z - A.x, ha = A.w - A.y;
                float xa = A.x + 0.5f * wa, ya = A.y + 0.5f * ha;
                float wt = t2 - t0, ht = t3 - t1;
                float xt = t0 + 0.5f * wt, yt = t1 + 0.5f * ht;
                float4 D = ((const float4*)rpn_deltas)[(size_t)b * N_ + i];
                regv += smooth_l1(D.x - (xt - xa) / wa) + smooth_l1(D.y - (yt - ya) / ha) +
                        smooth_l1(D.z - logf(wt / wa + 1e-6f)) + smooth_l1(D.w - logf(ht / ha + 1e-6f));
            }
        } else if (lab[j] == 0) {
            int r = pN++;
            if (r < negQ) {
                float l = rpn_scores[(size_t)b * N_ + i];
                bce += fmaxf(l, 0.f) + log1pf(expf(-fabsf(l)));
            }
        }
    }
    for (int m = 32; m >= 1; m >>= 1) { bce += __shfl_xor(bce, m); regv += __shfl_xor(regv, m); }
    if (lane == 0) { sred[wave] = bce; sred[4 + wave] = regv; }
    __syncthreads();
    if (tid == 0) {
        float sb = sred[0] + sred[1] + sred[2] + sred[3];
        float sr = sred[4] + sred[5] + sred[6] + sred[7];
        int rnp = min(totP, RPN_BATCH / 2);
        int kneg = min(totN, RPN_BATCH - rnp);
        float denomC = fmaxf((float)(rnp + kneg), 1.f);
        float contrib = sb / denomC +
                        ((rnp > 0) ? sr / fmaxf((float)rnp * 4.f, 1.f) : 0.f);
        if (blockIdx.x == 0)
            contrib += detPart[b * DETB + 0] + detPart[b * DETB + 1] +
                       detPart[b * DETB + 2] + detPart[b * DETB + 3];
        if (contrib != 0.f || blockIdx.x == 0) atomicAdd(out, contrib);
    }
}

extern "C" void kernel_launch(void* const* d_in, const int* in_sizes, int n_in,
                              void* d_out, int out_size, void* d_ws, size_t ws_size,
                              hipStream_t stream) {
    const float* rpn_scores  = (const float*)d_in[0];
    const float* rpn_deltas  = (const float*)d_in[1];
    const float* cls_scores  = (const float*)d_in[2];
    const float* bbox_deltas = (const float*)d_in[3];
    const float* anchors     = (const float*)d_in[4];
    const float* proposals   = (const float*)d_in[5];
    const float* gt_boxes    = (const float*)d_in[6];
    const int*   gt_labels   = (const int*)d_in[7];
    float* out = (float*)d_out;

    char* ws = (char*)d_ws;
    size_t off = 0;
    auto alloc = [&](size_t bytes) -> char* {
        size_t o = (off + 255) & ~(size_t)255;
        off = o + bytes;
        return ws + o;
    };
    int8_t* labels = (int8_t*)alloc((size_t)B_ * N_);
    int* posCnt = (int*)alloc((size_t)B_ * NBA * 4);
    int* negCnt = (int*)alloc((size_t)B_ * NBA * 4);
    unsigned long long* blockBest = (unsigned long long*)alloc((size_t)B_ * G_ * NBA * 8);
    float* detPart = (float*)alloc(B_ * DETB * 4);

    rpn_assign_det<<<dim3(NBA + DETB, B_), 512, 0, stream>>>(
            anchors, gt_boxes, gt_labels, proposals, cls_scores, bbox_deltas,
            labels, posCnt, negCnt, blockBest, detPart, out, out_size);
    rpn_sample<<<dim3(NBA, B_), 256, 0, stream>>>(labels, rpn_scores, rpn_deltas,
                                                  anchors, gt_boxes, posCnt, negCnt,
                                                  blockBest, detPart, out);
}